// Round 10
// baseline (710.705 us; speedup 1.0000x reference)
//
#include <hip/hip_runtime.h>
#include <hip/hip_bf16.h>
#include <math.h>

// Problem constants (SchNet reference)
#define NATOMS 16384
#define NMOL   512
#define APM    32
#define GDIM   50
#define KTAB   2048   // filter lookup-table knots over d in [0,6]
#define MAXU   512    // max undirected edges per molecule (496) padded

#define STRH 132      // s_h / s_agg row stride (floats), 528B: 132%32=4 rotates banks
#define STRA 136      // s_t row stride (ushorts), 272B

typedef __attribute__((ext_vector_type(8))) short   short8;   // 8 bf16 (A/B frag)
typedef __attribute__((ext_vector_type(4))) float   floatx4;  // C/D frag

// fast shifted softplus: log(1+exp(x)) - log2, via HW v_exp_f32/v_log_f32
__device__ __forceinline__ float ssp(float x) {
    float e = __expf(-fabsf(x));
    return fmaxf(x, 0.0f) + __logf(1.0f + e) - 0.69314718055994531f;
}

__device__ __forceinline__ unsigned short f2bf(float x) {
    union { float f; unsigned int u; } v; v.f = x;
    unsigned int lsb = (v.u >> 16) & 1u;
    v.u += 0x7fffu + lsb;
    return (unsigned short)(v.u >> 16);
}

__device__ __forceinline__ unsigned int pk2bf(float a, float b) {
    __hip_bfloat162 h = __float22bfloat162_rn(make_float2(a, b));
    unsigned int u;
    __builtin_memcpy(&u, &h, 4);
    return u;
}

// ---------------------------------------------------------------------------
// Combined setup: blocks [0,NMOL) compact undirected edges per molecule
// (ballot-compaction, wave 0 of each block); blocks >= NMOL convert weights
// to bf16 B-frag layout (9x128x128 + out1^T 64x128).
// meta word: knot<<12 | a<<6 | b  (a,b molecule-local; 32 = dummy/zero row)
// ---------------------------------------------------------------------------
__global__ __launch_bounds__(256) void setup_kernel(
    const float* __restrict__ pos, const int* __restrict__ eidx, int E,
    const float* __restrict__ cf1, const float* __restrict__ cf2,
    const float* __restrict__ lin, const float* __restrict__ out1,
    unsigned short* __restrict__ Wtall, uint2* __restrict__ umeta,
    int* __restrict__ ucnt)
{
    if (blockIdx.x < NMOL) {
        const int lane = threadIdx.x;
        if (lane >= 64) return;
        const int m  = blockIdx.x;
        const int B0 = m * 32;
        int lo = 0, hi = E;
        while (lo < hi) { int mid = (lo + hi) >> 1; if (eidx[mid] < B0) lo = mid + 1; else hi = mid; }
        const int e0 = lo; hi = E;
        while (lo < hi) { int mid = (lo + hi) >> 1; if (eidx[mid] < B0 + 32) lo = mid + 1; else hi = mid; }
        const int e1 = lo;

        uint2* out = umeta + (size_t)m * MAXU;
        int cnt = 0;
        for (int base = e0; base < e1; base += 64) {
            int e = base + lane;
            bool keep = false;
            uint2 val;
            if (e < e1) {
                int s = eidx[e], t = eidx[E + e];
                if (t > s) {
                    float dx = pos[3 * s]     - pos[3 * t];
                    float dy = pos[3 * s + 1] - pos[3 * t + 1];
                    float dz = pos[3 * s + 2] - pos[3 * t + 2];
                    float d  = sqrtf(dx * dx + dy * dy + dz * dz);
                    float u  = d * (float)(KTAB - 1) / 6.0f;
                    int i = min((int)u, KTAB - 2);
                    val = make_uint2(((unsigned)i << 12) |
                                     ((unsigned)(s - B0) << 6) | (unsigned)(t - B0),
                                     __float_as_uint(u - (float)i));
                    keep = true;
                }
            }
            unsigned long long mask = __ballot(keep);
            int slot = __popcll(mask & ((1ULL << lane) - 1ULL));
            if (keep) out[cnt + slot] = val;
            cnt += (int)__popcll(mask);
        }
        // pad to multiple of 64 with dummy edges (zero-row endpoints, fr=0)
        int padded = (cnt + 63) & ~63;
        for (int e = cnt + lane; e < padded; e += 64)
            out[e] = make_uint2((32u << 6) | 32u, 0u);
        if (lane == 0) ucnt[m] = padded;
        return;
    }
    int idx = (blockIdx.x - NMOL) * 256 + threadIdx.x;
    if (idx < 9 * 16384) {
        int wi = idx >> 14, rem = idx & 16383;
        int n = rem >> 7, k = rem & 127;
        int l = wi / 3, which = wi % 3;
        const float* src = (which == 0) ? cf1 : (which == 1) ? cf2 : lin;
        Wtall[idx] = f2bf(src[(size_t)l * 16384 + k * 128 + n]);
    } else if (idx < 9 * 16384 + 64 * 128) {
        int q = idx - 9 * 16384;
        int n = q >> 7, k = q & 127;
        Wtall[idx] = f2bf(out1[k * 64 + n]);
    }
}

// ---------------------------------------------------------------------------
// Build filter table: T[l][k][f] = ((ssp(ea(d_k)@w1+b1)@w2)+b2)*cut(d_k), bf16
// ---------------------------------------------------------------------------
#define KW1 72
#define KW2 136

__global__ __launch_bounds__(256, 2) void build_table_kernel(
    const float* __restrict__ w1_, const float* __restrict__ b1_,
    const float* __restrict__ w2_, const float* __restrict__ b2_,
    unsigned short* __restrict__ T_)
{
    const int l = blockIdx.y;
    const float* w1 = w1_ + (size_t)l * GDIM * 128;
    const float* b1 = b1_ + (size_t)l * 128;
    const float* w2 = w2_ + (size_t)l * 128 * 128;
    const float* b2 = b2_ + (size_t)l * 128;
    unsigned short* T = T_ + (size_t)l * KTAB * 128;

    __shared__ unsigned short s_w1T[128 * KW1];
    __shared__ unsigned short s_w2T[128 * KW2];
    __shared__ unsigned short s_t[64 * KW2];

    const int tid = threadIdx.x;
    for (int i = tid; i < GDIM * 128; i += 256) {
        int g = i >> 7, f = i & 127;
        s_w1T[f * KW1 + g] = f2bf(w1[i]);
    }
    for (int i = tid; i < (64 - GDIM) * 128; i += 256) {
        int g = GDIM + (i >> 7), f = i & 127;
        s_w1T[f * KW1 + g] = 0;
    }
    for (int i = tid; i < 128 * 128; i += 256) {
        int k = i >> 7, n = i & 127;
        s_w2T[n * KW2 + k] = f2bf(w2[i]);
    }

    const int lane = tid & 63;
    const int w    = tid >> 6;
    const int l15  = lane & 15;
    const int quad = lane >> 4;

    float b1v[8], b2v[8];
    #pragma unroll
    for (int nt = 0; nt < 8; nt++) {
        b1v[nt] = b1[nt * 16 + l15];
        b2v[nt] = b2[nt * 16 + l15];
    }
    __syncthreads();

    const float hstep = 6.0f / (float)(KTAB - 1);
    const float step  = 6.0f / 49.0f;
    const float coeff = -0.5f / (step * step);
    const float pioc  = 3.14159265358979323846f / 6.0f;
    const int k0 = blockIdx.x * 64;
    const float dm = (float)(k0 + w * 16 + l15) * hstep;

    floatx4 acc1[8];
    #pragma unroll
    for (int nt = 0; nt < 8; nt++) acc1[nt] = (floatx4){0.f, 0.f, 0.f, 0.f};
    #pragma unroll
    for (int ks = 0; ks < 2; ks++) {
        unsigned int ap[4];
        #pragma unroll
        for (int jj = 0; jj < 4; jj++) {
            int g0 = ks * 32 + quad * 8 + 2 * jj;
            float d0 = dm - (float)g0 * step;
            float d1 = dm - (float)(g0 + 1) * step;
            float v0 = (g0 < GDIM)     ? __expf(coeff * d0 * d0) : 0.0f;
            float v1 = (g0 + 1 < GDIM) ? __expf(coeff * d1 * d1) : 0.0f;
            ap[jj] = pk2bf(v0, v1);
        }
        short8 af;
        __builtin_memcpy(&af, ap, 16);
        #pragma unroll
        for (int nt = 0; nt < 8; nt++) {
            short8 bfg = *(const short8*)&s_w1T[(nt * 16 + l15) * KW1 + ks * 32 + quad * 8];
            acc1[nt] = __builtin_amdgcn_mfma_f32_16x16x32_bf16(af, bfg, acc1[nt], 0, 0, 0);
        }
    }
    #pragma unroll
    for (int nt = 0; nt < 8; nt++) {
        #pragma unroll
        for (int r = 0; r < 4; r++) {
            int row = w * 16 + quad * 4 + r;
            s_t[row * KW2 + nt * 16 + l15] = f2bf(ssp(acc1[nt][r] + b1v[nt]));
        }
    }
    // no barrier: wave reads only rows it wrote

    floatx4 acc2[8];
    #pragma unroll
    for (int nt = 0; nt < 8; nt++) acc2[nt] = (floatx4){0.f, 0.f, 0.f, 0.f};
    #pragma unroll
    for (int ks = 0; ks < 4; ks++) {
        short8 af = *(const short8*)&s_t[(w * 16 + l15) * KW2 + ks * 32 + quad * 8];
        #pragma unroll
        for (int nt = 0; nt < 8; nt++) {
            short8 bfg = *(const short8*)&s_w2T[(nt * 16 + l15) * KW2 + ks * 32 + quad * 8];
            acc2[nt] = __builtin_amdgcn_mfma_f32_16x16x32_bf16(af, bfg, acc2[nt], 0, 0, 0);
        }
    }

    #pragma unroll
    for (int nt = 0; nt < 8; nt++) {
        #pragma unroll
        for (int r = 0; r < 4; r++) {
            int row = w * 16 + quad * 4 + r;
            float d = (float)(k0 + row) * hstep;
            float cut = 0.5f * (__cosf(d * pioc) + 1.0f);
            T[(size_t)(k0 + row) * 128 + nt * 16 + l15] = f2bf((acc2[nt][r] + b2v[nt]) * cut);
        }
    }
}

// pack (w0, dw) knots: Tp[l][k][f] = T[k][f] | bf16(T[k+1][f]-T[k][f])<<16
__global__ __launch_bounds__(256) void pack_table_kernel(
    const unsigned short* __restrict__ T, unsigned int* __restrict__ Tp)
{
    int idx = blockIdx.x * 256 + threadIdx.x;    // over 3*KTAB*128
    int k = (idx >> 7) & (KTAB - 1);
    unsigned int w0 = T[idx];
    float w0f = __uint_as_float(w0 << 16);
    float w1f = (k == KTAB - 1) ? w0f
              : __uint_as_float((unsigned int)T[idx + 128] << 16);
    unsigned int dw = f2bf(w1f - w0f);
    Tp[idx] = w0 | (dw << 16);
}

// ---------------------------------------------------------------------------
// Fully-fused SchNet: one block = one molecule, 512 threads = 8 waves
// (2 blocks/CU -> 16 waves/CU). GEMM tile per wave: rows (w&1)*16,
// cols (w>>1)*32. Gather: UNDIRECTED edge-parallel (each pair computed
// once -> 1 Tp load + 1 lerp serves both endpoints), fp32 LDS atomics,
// edge list padded to x64 so the 8-deep unroll has no tail divergence.
// ---------------------------------------------------------------------------
__global__ __launch_bounds__(512) void fused_schnet_kernel(
    const int* __restrict__ z, const float* __restrict__ emb,
    const uint2* __restrict__ umeta, const int* __restrict__ ucnt,
    const unsigned int* __restrict__ Tp,
    const unsigned short* __restrict__ Wtall,
    const float* __restrict__ cf2_b, const float* __restrict__ lin_b,
    const float* __restrict__ out1_b, const float* __restrict__ out2_w,
    const float* __restrict__ out2_b,
    float* __restrict__ out)
{
    __shared__ float s_h[32 * STRH];                 // 16.9 KB fp32 node state
    __shared__ float s_hx[33 * 128];                 // 16.9 KB; row 32 = zeros
    __shared__ float s_agg[33 * STRH];               // 17.4 KB fp32; row 32 = sink
    __shared__ uint2 s_meta[MAXU];                   //  4.0 KB
    __shared__ float s_red;
    unsigned short* s_t = (unsigned short*)s_hx;     // [32][STRA] bf16 alias
                                                     // (first 8.7KB; zero row safe)
    const int tid  = threadIdx.x;
    const int lane = tid & 63;
    const int w    = tid >> 6;          // wave 0..7
    const int l15  = lane & 15;
    const int quad = lane >> 4;
    const int r16  = (w & 1) * 16;      // GEMM row tile
    const int c32  = (w >> 1) * 32;     // GEMM col tile
    const int B0   = blockIdx.x * 32;   // molecule base atom

    // init h from embedding; zero the hx dummy row
    for (int i = tid; i < 32 * 128; i += 512) {
        int row = i >> 7, col = i & 127;
        s_h[row * STRH + col] = emb[(size_t)z[B0 + row] * 128 + col];
    }
    if (tid < 128) s_hx[32 * 128 + tid] = 0.0f;
    if (tid == 0) s_red = 0.0f;

    // stage undirected edge metadata (layer-invariant)
    const int nU = ucnt[blockIdx.x];
    for (int i = tid; i < nU; i += 512) s_meta[i] = umeta[(size_t)blockIdx.x * MAXU + i];

    const unsigned short* WtO = Wtall + 9 * 16384;   // out1^T

    for (int l = 0; l < 3; l++) {
        const unsigned short* W1 = Wtall + (size_t)(l * 3 + 0) * 16384;
        const unsigned short* W2 = Wtall + (size_t)(l * 3 + 1) * 16384;
        const unsigned short* W3 = Wtall + (size_t)(l * 3 + 2) * 16384;
        const unsigned int* Tpl  = Tp + (size_t)l * KTAB * 128;

        __syncthreads();   // h ready; prev-layer s_agg consumed; meta staged

        // zero s_agg rows 0..31 (row 32 is a write-sink, never read)
        for (int i = tid; i < 32 * STRH; i += 512) s_agg[i] = 0.0f;

        // ---- GEMM1: hx = h @ cf1 (16x32 tile per wave) ----
        floatx4 acc[2];
        #pragma unroll
        for (int nt = 0; nt < 2; nt++) acc[nt] = (floatx4){0.f, 0.f, 0.f, 0.f};
        #pragma unroll
        for (int ks = 0; ks < 4; ks++) {
            const float* hp = &s_h[(r16 + l15) * STRH + ks * 32 + quad * 8];
            float4 xa = *(const float4*)hp;
            float4 xb = *(const float4*)(hp + 4);
            unsigned int ap[4];
            ap[0] = pk2bf(xa.x, xa.y); ap[1] = pk2bf(xa.z, xa.w);
            ap[2] = pk2bf(xb.x, xb.y); ap[3] = pk2bf(xb.z, xb.w);
            short8 af;
            __builtin_memcpy(&af, ap, 16);
            #pragma unroll
            for (int nt = 0; nt < 2; nt++) {
                short8 bfg = *(const short8*)&W1[(size_t)(c32 + nt * 16 + l15) * 128 + ks * 32 + quad * 8];
                acc[nt] = __builtin_amdgcn_mfma_f32_16x16x32_bf16(af, bfg, acc[nt], 0, 0, 0);
            }
        }
        #pragma unroll
        for (int nt = 0; nt < 2; nt++) {
            #pragma unroll
            for (int r = 0; r < 4; r++)
                s_hx[(r16 + quad * 4 + r) * 128 + c32 + nt * 16 + l15] = acc[nt][r];
        }

        __syncthreads();   // hx + zeroed agg ready

        // ---- undirected gather: 1 lerp per pair, scatter to both ends ----
        for (int base = w * 8; base < nU; base += 64) {
            #pragma unroll
            for (int j = 0; j < 8; j++) {
                uint2 q = s_meta[base + j];
                int b    = q.x & 63;
                int a    = (q.x >> 6) & 63;
                int knot = q.x >> 12;
                uint2 tp = *(const uint2*)&Tpl[(size_t)knot * 128 + 2 * lane];
                float2 hva = *(const float2*)&s_hx[a * 128 + 2 * lane];
                float2 hvb = *(const float2*)&s_hx[b * 128 + 2 * lane];
                float fr = __uint_as_float(q.y);
                float wx = fmaf(fr, __uint_as_float(tp.x & 0xffff0000u),
                                __uint_as_float(tp.x << 16));
                float wy = fmaf(fr, __uint_as_float(tp.y & 0xffff0000u),
                                __uint_as_float(tp.y << 16));
                atomicAdd(&s_agg[a * STRH + 2 * lane],     hvb.x * wx);
                atomicAdd(&s_agg[a * STRH + 2 * lane + 1], hvb.y * wy);
                atomicAdd(&s_agg[b * STRH + 2 * lane],     hva.x * wx);
                atomicAdd(&s_agg[b * STRH + 2 * lane + 1], hva.y * wy);
            }
        }

        __syncthreads();   // agg complete; hx reads done (s_t alias safe)

        // ---- GEMM2: t = ssp(agg @ cf2 + b) ----
        float bva[2], bvb[2];
        #pragma unroll
        for (int nt = 0; nt < 2; nt++) {
            bva[nt] = cf2_b[l * 128 + c32 + nt * 16 + l15];
            bvb[nt] = lin_b[l * 128 + c32 + nt * 16 + l15];
        }
        #pragma unroll
        for (int nt = 0; nt < 2; nt++) acc[nt] = (floatx4){0.f, 0.f, 0.f, 0.f};
        #pragma unroll
        for (int ks = 0; ks < 4; ks++) {
            const float* apf = &s_agg[(r16 + l15) * STRH + ks * 32 + quad * 8];
            float4 xa = *(const float4*)apf;
            float4 xb = *(const float4*)(apf + 4);
            unsigned int ap[4];
            ap[0] = pk2bf(xa.x, xa.y); ap[1] = pk2bf(xa.z, xa.w);
            ap[2] = pk2bf(xb.x, xb.y); ap[3] = pk2bf(xb.z, xb.w);
            short8 af;
            __builtin_memcpy(&af, ap, 16);
            #pragma unroll
            for (int nt = 0; nt < 2; nt++) {
                short8 bfg = *(const short8*)&W2[(size_t)(c32 + nt * 16 + l15) * 128 + ks * 32 + quad * 8];
                acc[nt] = __builtin_amdgcn_mfma_f32_16x16x32_bf16(af, bfg, acc[nt], 0, 0, 0);
            }
        }
        #pragma unroll
        for (int nt = 0; nt < 2; nt++) {
            #pragma unroll
            for (int r = 0; r < 4; r++) {
                int row = r16 + quad * 4 + r;
                s_t[row * STRA + c32 + nt * 16 + l15] = f2bf(ssp(acc[nt][r] + bva[nt]));
            }
        }

        __syncthreads();   // t complete (cross-wave cols needed by GEMM3)

        // ---- GEMM3: h += t @ lin + b ----
        #pragma unroll
        for (int nt = 0; nt < 2; nt++) acc[nt] = (floatx4){0.f, 0.f, 0.f, 0.f};
        #pragma unroll
        for (int ks = 0; ks < 4; ks++) {
            short8 af = *(const short8*)&s_t[(r16 + l15) * STRA + ks * 32 + quad * 8];
            #pragma unroll
            for (int nt = 0; nt < 2; nt++) {
                short8 bfg = *(const short8*)&W3[(size_t)(c32 + nt * 16 + l15) * 128 + ks * 32 + quad * 8];
                acc[nt] = __builtin_amdgcn_mfma_f32_16x16x32_bf16(af, bfg, acc[nt], 0, 0, 0);
            }
        }
        #pragma unroll
        for (int nt = 0; nt < 2; nt++) {
            #pragma unroll
            for (int r = 0; r < 4; r++) {
                int row = r16 + quad * 4 + r;
                s_h[row * STRH + c32 + nt * 16 + l15] += acc[nt][r] + bvb[nt];
            }
        }
        // loop-top __syncthreads covers h
    }

    __syncthreads();

    // ---- head: out = sum_a ssp(h@out1 + b1)@out2 + 32*b2 ----
    const int c16 = (w >> 1) * 16;   // out1: 64 cols = 4 col tiles x 2 row tiles
    floatx4 ha = (floatx4){0.f, 0.f, 0.f, 0.f};
    #pragma unroll
    for (int ks = 0; ks < 4; ks++) {
        const float* hp = &s_h[(r16 + l15) * STRH + ks * 32 + quad * 8];
        float4 xa = *(const float4*)hp;
        float4 xb = *(const float4*)(hp + 4);
        unsigned int ap[4];
        ap[0] = pk2bf(xa.x, xa.y); ap[1] = pk2bf(xa.z, xa.w);
        ap[2] = pk2bf(xb.x, xb.y); ap[3] = pk2bf(xb.z, xb.w);
        short8 af;
        __builtin_memcpy(&af, ap, 16);
        short8 bfg = *(const short8*)&WtO[(size_t)(c16 + l15) * 128 + ks * 32 + quad * 8];
        ha = __builtin_amdgcn_mfma_f32_16x16x32_bf16(af, bfg, ha, 0, 0, 0);
    }
    float part = 0.0f;
    {
        float b1o = out1_b[c16 + l15];
        float o2  = out2_w[c16 + l15];
        #pragma unroll
        for (int r = 0; r < 4; r++)
            part += ssp(ha[r] + b1o) * o2;
    }
    #pragma unroll
    for (int off = 32; off > 0; off >>= 1) part += __shfl_down(part, off);
    if (lane == 0) atomicAdd(&s_red, part);
    __syncthreads();
    if (tid == 0) out[blockIdx.x] = s_red + 32.0f * out2_b[0];
}

extern "C" void kernel_launch(void* const* d_in, const int* in_sizes, int n_in,
                              void* d_out, int out_size, void* d_ws, size_t ws_size,
                              hipStream_t stream)
{
    const int*   z      = (const int*)d_in[0];
    const float* pos    = (const float*)d_in[1];
    const int*   eidx   = (const int*)d_in[3];
    const float* emb    = (const float*)d_in[4];
    const float* mlp_w1 = (const float*)d_in[5];
    const float* mlp_b1 = (const float*)d_in[6];
    const float* mlp_w2 = (const float*)d_in[7];
    const float* mlp_b2 = (const float*)d_in[8];
    const float* cf1_w  = (const float*)d_in[9];
    const float* cf2_w  = (const float*)d_in[10];
    const float* cf2_b  = (const float*)d_in[11];
    const float* lin_w  = (const float*)d_in[12];
    const float* lin_b  = (const float*)d_in[13];
    const float* out1_w = (const float*)d_in[14];
    const float* out1_b = (const float*)d_in[15];
    const float* out2_w = (const float*)d_in[16];
    const float* out2_b = (const float*)d_in[17];
    const int E = in_sizes[3] / 2;

    // workspace carve-up (16B-aligned sections)
    char* p = (char*)d_ws;
    uint2* umeta = (uint2*)p;                     p += (size_t)NMOL * MAXU * 8;
    unsigned int* Tp = (unsigned int*)p;          p += (size_t)3 * KTAB * 128 * 4;
    int* ucnt = (int*)p;                          p += ((size_t)NMOL * 4 + 63) & ~63ULL;
    unsigned short* Ttab = (unsigned short*)p;    p += (size_t)3 * KTAB * 128 * 2;
    unsigned short* Wtall = (unsigned short*)p;   // 9*16384 + 64*128 ushorts

    const int wblocks = (9 * 16384 + 64 * 128 + 255) / 256;
    setup_kernel<<<NMOL + wblocks, 256, 0, stream>>>(
        pos, eidx, E, cf1_w, cf2_w, lin_w, out1_w, Wtall, umeta, ucnt);
    build_table_kernel<<<dim3(KTAB / 64, 3), 256, 0, stream>>>(
        mlp_w1, mlp_b1, mlp_w2, mlp_b2, Ttab);
    pack_table_kernel<<<3 * KTAB * 128 / 256, 256, 0, stream>>>(Ttab, Tp);

    fused_schnet_kernel<<<NMOL, 512, 0, stream>>>(
        z, emb, umeta, ucnt, Tp, Wtall,
        cf2_b, lin_b, out1_b, out2_w, out2_b, (float*)d_out);
}

// Round 11
// 180.675 us; speedup vs baseline: 3.9336x; 3.9336x over previous
//
#include <hip/hip_runtime.h>
#include <hip/hip_bf16.h>
#include <math.h>

// Problem constants (SchNet reference)
#define NATOMS 16384
#define NMOL   512
#define APM    32
#define GDIM   50
#define KTAB   2048   // filter lookup-table knots over d in [0,6]
#define MAXEPM 1000   // max edges per molecule (992) + sentinel

#define STRH 132      // s_h row stride (floats), 528B
#define STRA 136      // s_agg / s_t row stride (ushorts), 272B

typedef __attribute__((ext_vector_type(8))) short   short8;   // 8 bf16 (A/B frag)
typedef __attribute__((ext_vector_type(4))) float   floatx4;  // C/D frag

// fast shifted softplus: log(1+exp(x)) - log2, via HW v_exp_f32/v_log_f32
__device__ __forceinline__ float ssp(float x) {
    float e = __expf(-fabsf(x));
    return fmaxf(x, 0.0f) + __logf(1.0f + e) - 0.69314718055994531f;
}

__device__ __forceinline__ unsigned short f2bf(float x) {
    union { float f; unsigned int u; } v; v.f = x;
    unsigned int lsb = (v.u >> 16) & 1u;
    v.u += 0x7fffu + lsb;
    return (unsigned short)(v.u >> 16);
}

__device__ __forceinline__ float bf2f(unsigned int u16bits) {
    union { unsigned int u; float f; } v; v.u = u16bits << 16;
    return v.f;
}

__device__ __forceinline__ unsigned int pk2bf(float a, float b) {
    __hip_bfloat162 h = __float22bfloat162_rn(make_float2(a, b));
    unsigned int u;
    __builtin_memcpy(&u, &h, 4);
    return u;
}

// ---------------------------------------------------------------------------
// MEGA-SETUP (single dispatch, 3 block regions):
//  [0,EB):        per-edge meta {knot<<6 | dst&63, frac} + sentinel + rowptr
//  [EB,EB+WB):    weights fp32 -> bf16 B-frag transpose (9x128x128 + out1 64x128)
//  [EB+WB, +99):  filter table, 33 tiles x 3 layers; tiles overlap by 1 knot
//                 and write packed Tp = (w0 | bf16(T[k+1]-T[k])<<16) directly.
// ---------------------------------------------------------------------------
#define KW1 72
#define KW2 136
#define TILE_K 63     // knots advanced per table tile (64 computed, 63 written)
#define NTILE 33      // ceil((KTAB-1)/63)

__global__ __launch_bounds__(256) void mega_setup_kernel(
    const float* __restrict__ pos, const int* __restrict__ eidx, int E, int EB,
    int* __restrict__ rowptr,
    const float* __restrict__ cf1, const float* __restrict__ cf2,
    const float* __restrict__ lin, const float* __restrict__ out1,
    unsigned short* __restrict__ Wtall, uint2* __restrict__ meta,
    const float* __restrict__ w1_, const float* __restrict__ b1_,
    const float* __restrict__ w2_, const float* __restrict__ b2_,
    unsigned int* __restrict__ Tp)
{
    const int WB = (9 * 16384 + 64 * 128 + 255) / 256;
    const int b = blockIdx.x;
    const int tid = threadIdx.x;

    if (b < EB) {
        int idx = b * 256 + tid;
        if (idx < E) {
            int s = eidx[idx], t = eidx[E + idx];
            float dx = pos[3 * s]     - pos[3 * t];
            float dy = pos[3 * s + 1] - pos[3 * t + 1];
            float dz = pos[3 * s + 2] - pos[3 * t + 2];
            float d  = sqrtf(dx * dx + dy * dy + dz * dz);
            float u  = d * (float)(KTAB - 1) / 6.0f;
            int i = min((int)u, KTAB - 2);
            meta[idx] = make_uint2(((unsigned)i << 6) | (unsigned)(t & 31),
                                   __float_as_uint(u - (float)i));
        } else if (idx < E + NATOMS + 1) {
            int a = idx - E;
            if (a == 0) meta[E] = make_uint2(32u, 0u);   // global sentinel (unused)
            int lo = 0, hi = E;
            while (lo < hi) { int mid = (lo + hi) >> 1; if (eidx[mid] < a) lo = mid + 1; else hi = mid; }
            rowptr[a] = lo;
        }
        return;
    }
    if (b < EB + WB) {
        int idx = (b - EB) * 256 + tid;
        if (idx < 9 * 16384) {
            int wi = idx >> 14, rem = idx & 16383;
            int n = rem >> 7, k = rem & 127;
            int l = wi / 3, which = wi % 3;
            const float* src = (which == 0) ? cf1 : (which == 1) ? cf2 : lin;
            Wtall[idx] = f2bf(src[(size_t)l * 16384 + k * 128 + n]);
        } else if (idx < 9 * 16384 + 64 * 128) {
            int q = idx - 9 * 16384;
            int n = q >> 7, k = q & 127;
            Wtall[idx] = f2bf(out1[k * 64 + n]);
        }
        return;
    }

    // ---------------- table region: t = (layer, tile) ----------------
    __shared__ unsigned short s_bufA[128 * KW2];   // w2T (34.8 KB)
    __shared__ unsigned short s_bufB[128 * KW1];   // w1T, then s_t / T_lds (alias)

    const int tt = b - EB - WB;
    const int l  = tt / NTILE;
    const int bx = tt % NTILE;
    const float* w1 = w1_ + (size_t)l * GDIM * 128;
    const float* b1 = b1_ + (size_t)l * 128;
    const float* w2 = w2_ + (size_t)l * 128 * 128;
    const float* b2 = b2_ + (size_t)l * 128;
    unsigned int* Tpg = Tp + (size_t)l * KTAB * 128;

    unsigned short* s_w1T = s_bufB;                // [128][KW1]
    unsigned short* s_w2T = s_bufA;                // [128][KW2]
    unsigned short* s_t   = s_bufB;                // [64][KW2] (after barrier)

    for (int i = tid; i < GDIM * 128; i += 256) {
        int g = i >> 7, f = i & 127;
        s_w1T[f * KW1 + g] = f2bf(w1[i]);
    }
    for (int i = tid; i < (64 - GDIM) * 128; i += 256) {
        int g = GDIM + (i >> 7), f = i & 127;
        s_w1T[f * KW1 + g] = 0;
    }
    for (int i = tid; i < 128 * 128; i += 256) {
        int k = i >> 7, n = i & 127;
        s_w2T[n * KW2 + k] = f2bf(w2[i]);
    }

    const int lane = tid & 63;
    const int w    = tid >> 6;
    const int l15  = lane & 15;
    const int quad = lane >> 4;

    float b1v[8], b2v[8];
    #pragma unroll
    for (int nt = 0; nt < 8; nt++) {
        b1v[nt] = b1[nt * 16 + l15];
        b2v[nt] = b2[nt * 16 + l15];
    }
    __syncthreads();

    const float hstep = 6.0f / (float)(KTAB - 1);
    const float step  = 6.0f / 49.0f;
    const float coeff = -0.5f / (step * step);
    const float pioc  = 3.14159265358979323846f / 6.0f;
    const int k0 = bx * TILE_K;
    const float dm = (float)(k0 + w * 16 + l15) * hstep;

    floatx4 acc1[8];
    #pragma unroll
    for (int nt = 0; nt < 8; nt++) acc1[nt] = (floatx4){0.f, 0.f, 0.f, 0.f};
    #pragma unroll
    for (int ks = 0; ks < 2; ks++) {
        unsigned int ap[4];
        #pragma unroll
        for (int jj = 0; jj < 4; jj++) {
            int g0 = ks * 32 + quad * 8 + 2 * jj;
            float d0 = dm - (float)g0 * step;
            float d1 = dm - (float)(g0 + 1) * step;
            float v0 = (g0 < GDIM)     ? __expf(coeff * d0 * d0) : 0.0f;
            float v1 = (g0 + 1 < GDIM) ? __expf(coeff * d1 * d1) : 0.0f;
            ap[jj] = pk2bf(v0, v1);
        }
        short8 af;
        __builtin_memcpy(&af, ap, 16);
        #pragma unroll
        for (int nt = 0; nt < 8; nt++) {
            short8 bfg = *(const short8*)&s_w1T[(nt * 16 + l15) * KW1 + ks * 32 + quad * 8];
            acc1[nt] = __builtin_amdgcn_mfma_f32_16x16x32_bf16(af, bfg, acc1[nt], 0, 0, 0);
        }
    }
    __syncthreads();   // all waves done reading s_w1T; s_t may alias it

    #pragma unroll
    for (int nt = 0; nt < 8; nt++) {
        #pragma unroll
        for (int r = 0; r < 4; r++) {
            int row = w * 16 + quad * 4 + r;
            s_t[row * KW2 + nt * 16 + l15] = f2bf(ssp(acc1[nt][r] + b1v[nt]));
        }
    }
    // no barrier: wave reads only rows it wrote

    floatx4 acc2[8];
    #pragma unroll
    for (int nt = 0; nt < 8; nt++) acc2[nt] = (floatx4){0.f, 0.f, 0.f, 0.f};
    #pragma unroll
    for (int ks = 0; ks < 4; ks++) {
        short8 af = *(const short8*)&s_t[(w * 16 + l15) * KW2 + ks * 32 + quad * 8];
        #pragma unroll
        for (int nt = 0; nt < 8; nt++) {
            short8 bfg = *(const short8*)&s_w2T[(nt * 16 + l15) * KW2 + ks * 32 + quad * 8];
            acc2[nt] = __builtin_amdgcn_mfma_f32_16x16x32_bf16(af, bfg, acc2[nt], 0, 0, 0);
        }
    }

    // write bf16 T tile into T_lds (alias of s_t; own rows only)
    unsigned short* T_lds = s_t;
    #pragma unroll
    for (int nt = 0; nt < 8; nt++) {
        #pragma unroll
        for (int r = 0; r < 4; r++) {
            int row = w * 16 + quad * 4 + r;
            float d = (float)(k0 + row) * hstep;
            float cut = 0.5f * (__cosf(d * pioc) + 1.0f);
            T_lds[row * KW2 + nt * 16 + l15] = f2bf((acc2[nt][r] + b2v[nt]) * cut);
        }
    }
    __syncthreads();

    // pack 63 Tp entries (w0, dw) from neighbor rows
    for (int i = tid; i < TILE_K * 128; i += 256) {
        int r = i >> 7, f = i & 127;
        int k = k0 + r;
        if (k <= KTAB - 2) {
            unsigned int w0 = T_lds[r * KW2 + f];
            unsigned int w1b = T_lds[(r + 1) * KW2 + f];
            unsigned int dw = f2bf(bf2f(w1b) - bf2f(w0));
            Tpg[(size_t)k * 128 + f] = w0 | (dw << 16);
        }
    }
}

// ---------------------------------------------------------------------------
// Fully-fused SchNet: one block = one molecule, 512 threads = 8 waves.
// GEMM tile per wave: rows (w&1)*16, cols (w>>1)*32. Gather: directed,
// register accumulation; HALF-WAVE EDGE PAIRING: lanes 0-31 = edge e,
// lanes 32-63 = edge e+1, 4 channels/lane (dwordx4 Tp + ds_read_b128 hx);
// 8-deep unroll = 16 edges per batch, sentinel (zero row 32) kills tails.
// ---------------------------------------------------------------------------
__global__ __launch_bounds__(512, 4) void fused_schnet_kernel(
    const int* __restrict__ z, const float* __restrict__ emb,
    const int* __restrict__ rowptr, const uint2* __restrict__ meta,
    const unsigned int* __restrict__ Tp,
    const unsigned short* __restrict__ Wtall,
    const float* __restrict__ cf2_b, const float* __restrict__ lin_b,
    const float* __restrict__ out1_b, const float* __restrict__ out2_w,
    const float* __restrict__ out2_b,
    float* __restrict__ out)
{
    __shared__ float s_h[32 * STRH];                 // 16.9 KB fp32 node state
    __shared__ float s_hx[33 * 128];                 // 16.9 KB; row 32 = zeros
    __shared__ unsigned short s_agg[32 * STRA];      //  8.7 KB bf16
    __shared__ uint2 s_meta[MAXEPM];                 //  8.0 KB
    __shared__ float s_red;
    unsigned short* s_t = (unsigned short*)s_hx;     // [32][STRA] alias (first 8.7KB)

    const int tid  = threadIdx.x;
    const int lane = tid & 63;
    const int w    = tid >> 6;          // wave 0..7
    const int l15  = lane & 15;
    const int quad = lane >> 4;
    const int r16  = (w & 1) * 16;      // GEMM row tile
    const int c32  = (w >> 1) * 32;     // GEMM col tile
    const int pair = lane >> 5;         // half-wave: which edge of the pair
    const int c4   = (lane & 31) * 4;   // 4 channels per lane
    const int B0   = blockIdx.x * 32;   // molecule base atom

    // init h; zero hx dummy row
    for (int i = tid; i < 32 * 128; i += 512) {
        int row = i >> 7, col = i & 127;
        s_h[row * STRH + col] = emb[(size_t)z[B0 + row] * 128 + col];
    }
    if (tid < 128) s_hx[32 * 128 + tid] = 0.0f;
    if (tid == 0) s_red = 0.0f;

    // stage edge metadata + local sentinel
    const int ebase = rowptr[B0];
    const int nE    = rowptr[B0 + 32] - ebase;
    for (int i = tid; i < nE; i += 512) s_meta[i] = meta[ebase + i];
    if (tid == 0) s_meta[nE] = make_uint2(32u, 0u);   // knot 0, row 32, fr 0

    // local row pointers for this wave's 4 atoms (5 bounds in lanes 0..4)
    const int rp = rowptr[B0 + w * 4 + min(lane, 4)] - ebase;

    const unsigned short* WtO = Wtall + 9 * 16384;   // out1^T

    for (int l = 0; l < 3; l++) {
        const unsigned short* W1 = Wtall + (size_t)(l * 3 + 0) * 16384;
        const unsigned short* W2 = Wtall + (size_t)(l * 3 + 1) * 16384;
        const unsigned short* W3 = Wtall + (size_t)(l * 3 + 2) * 16384;
        const unsigned int* Tpl  = Tp + (size_t)l * KTAB * 128;

        __syncthreads();   // h ready (also covers init/meta staging at l=0)

        // ---- GEMM1: hx = h @ cf1 (16x32 tile per wave) ----
        floatx4 acc[2];
        #pragma unroll
        for (int nt = 0; nt < 2; nt++) acc[nt] = (floatx4){0.f, 0.f, 0.f, 0.f};
        #pragma unroll
        for (int ks = 0; ks < 4; ks++) {
            const float* hp = &s_h[(r16 + l15) * STRH + ks * 32 + quad * 8];
            float4 xa = *(const float4*)hp;
            float4 xb = *(const float4*)(hp + 4);
            unsigned int ap[4];
            ap[0] = pk2bf(xa.x, xa.y); ap[1] = pk2bf(xa.z, xa.w);
            ap[2] = pk2bf(xb.x, xb.y); ap[3] = pk2bf(xb.z, xb.w);
            short8 af;
            __builtin_memcpy(&af, ap, 16);
            #pragma unroll
            for (int nt = 0; nt < 2; nt++) {
                short8 bfg = *(const short8*)&W1[(size_t)(c32 + nt * 16 + l15) * 128 + ks * 32 + quad * 8];
                acc[nt] = __builtin_amdgcn_mfma_f32_16x16x32_bf16(af, bfg, acc[nt], 0, 0, 0);
            }
        }
        #pragma unroll
        for (int nt = 0; nt < 2; nt++) {
            #pragma unroll
            for (int r = 0; r < 4; r++)
                s_hx[(r16 + quad * 4 + r) * 128 + c32 + nt * 16 + l15] = acc[nt][r];
        }

        __syncthreads();   // hx complete before gather reads

        // ---- gather: wave per 4 atoms, half-wave edge pairing ----
        for (int al = 0; al < 4; al++) {
            const int e0 = __shfl(rp, al);
            const int e1 = __shfl(rp, al + 1);
            float a0[8], a1[8], a2[8], a3[8];
            #pragma unroll
            for (int j = 0; j < 8; j++) { a0[j] = a1[j] = a2[j] = a3[j] = 0.f; }
            for (int e = e0; e < e1; e += 16) {
                #pragma unroll
                for (int j = 0; j < 8; j++) {
                    int idx = e + 2 * j + pair;
                    idx = (idx < e1) ? idx : nE;           // sentinel -> zero row
                    uint2 q = s_meta[idx];
                    int tl   = q.x & 63;
                    int knot = q.x >> 6;
                    uint4 tp = *(const uint4*)&Tpl[(size_t)knot * 128 + c4];
                    float4 hv = *(const float4*)&s_hx[tl * 128 + c4];
                    float fr = __uint_as_float(q.y);
                    a0[j] = fmaf(hv.x, fmaf(fr, __uint_as_float(tp.x & 0xffff0000u),
                                            __uint_as_float(tp.x << 16)), a0[j]);
                    a1[j] = fmaf(hv.y, fmaf(fr, __uint_as_float(tp.y & 0xffff0000u),
                                            __uint_as_float(tp.y << 16)), a1[j]);
                    a2[j] = fmaf(hv.z, fmaf(fr, __uint_as_float(tp.z & 0xffff0000u),
                                            __uint_as_float(tp.z << 16)), a2[j]);
                    a3[j] = fmaf(hv.w, fmaf(fr, __uint_as_float(tp.w & 0xffff0000u),
                                            __uint_as_float(tp.w << 16)), a3[j]);
                }
            }
            float s0 = ((a0[0] + a0[1]) + (a0[2] + a0[3])) + ((a0[4] + a0[5]) + (a0[6] + a0[7]));
            float s1 = ((a1[0] + a1[1]) + (a1[2] + a1[3])) + ((a1[4] + a1[5]) + (a1[6] + a1[7]));
            float s2 = ((a2[0] + a2[1]) + (a2[2] + a2[3])) + ((a2[4] + a2[5]) + (a2[6] + a2[7]));
            float s3 = ((a3[0] + a3[1]) + (a3[2] + a3[3])) + ((a3[4] + a3[5]) + (a3[6] + a3[7]));
            s0 += __shfl_xor(s0, 32);
            s1 += __shfl_xor(s1, 32);
            s2 += __shfl_xor(s2, 32);
            s3 += __shfl_xor(s3, 32);
            if (pair == 0) {
                uint2 pkd = make_uint2(pk2bf(s0, s1), pk2bf(s2, s3));
                *(uint2*)&s_agg[(w * 4 + al) * STRA + c4] = pkd;
            }
        }

        __syncthreads();   // agg complete; hx reads done (s_t alias safe)

        // ---- GEMM2: t = ssp(agg @ cf2 + b) ----
        float bva[2], bvb[2];
        #pragma unroll
        for (int nt = 0; nt < 2; nt++) {
            bva[nt] = cf2_b[l * 128 + c32 + nt * 16 + l15];
            bvb[nt] = lin_b[l * 128 + c32 + nt * 16 + l15];
        }
        #pragma unroll
        for (int nt = 0; nt < 2; nt++) acc[nt] = (floatx4){0.f, 0.f, 0.f, 0.f};
        #pragma unroll
        for (int ks = 0; ks < 4; ks++) {
            short8 af = *(const short8*)&s_agg[(r16 + l15) * STRA + ks * 32 + quad * 8];
            #pragma unroll
            for (int nt = 0; nt < 2; nt++) {
                short8 bfg = *(const short8*)&W2[(size_t)(c32 + nt * 16 + l15) * 128 + ks * 32 + quad * 8];
                acc[nt] = __builtin_amdgcn_mfma_f32_16x16x32_bf16(af, bfg, acc[nt], 0, 0, 0);
            }
        }
        #pragma unroll
        for (int nt = 0; nt < 2; nt++) {
            #pragma unroll
            for (int r = 0; r < 4; r++) {
                int row = r16 + quad * 4 + r;
                s_t[row * STRA + c32 + nt * 16 + l15] = f2bf(ssp(acc[nt][r] + bva[nt]));
            }
        }

        __syncthreads();   // t complete (cross-wave cols needed by GEMM3)

        // ---- GEMM3: h += t @ lin + b ----
        #pragma unroll
        for (int nt = 0; nt < 2; nt++) acc[nt] = (floatx4){0.f, 0.f, 0.f, 0.f};
        #pragma unroll
        for (int ks = 0; ks < 4; ks++) {
            short8 af = *(const short8*)&s_t[(r16 + l15) * STRA + ks * 32 + quad * 8];
            #pragma unroll
            for (int nt = 0; nt < 2; nt++) {
                short8 bfg = *(const short8*)&W3[(size_t)(c32 + nt * 16 + l15) * 128 + ks * 32 + quad * 8];
                acc[nt] = __builtin_amdgcn_mfma_f32_16x16x32_bf16(af, bfg, acc[nt], 0, 0, 0);
            }
        }
        #pragma unroll
        for (int nt = 0; nt < 2; nt++) {
            #pragma unroll
            for (int r = 0; r < 4; r++) {
                int row = r16 + quad * 4 + r;
                s_h[row * STRH + c32 + nt * 16 + l15] += acc[nt][r] + bvb[nt];
            }
        }
        // loop-top __syncthreads covers h
    }

    __syncthreads();

    // ---- head: out = sum_a ssp(h@out1 + b1)@out2 + 32*b2 ----
    const int c16 = (w >> 1) * 16;   // out1: 64 cols = 4 col tiles x 2 row tiles
    floatx4 ha = (floatx4){0.f, 0.f, 0.f, 0.f};
    #pragma unroll
    for (int ks = 0; ks < 4; ks++) {
        const float* hp = &s_h[(r16 + l15) * STRH + ks * 32 + quad * 8];
        float4 xa = *(const float4*)hp;
        float4 xb = *(const float4*)(hp + 4);
        unsigned int ap[4];
        ap[0] = pk2bf(xa.x, xa.y); ap[1] = pk2bf(xa.z, xa.w);
        ap[2] = pk2bf(xb.x, xb.y); ap[3] = pk2bf(xb.z, xb.w);
        short8 af;
        __builtin_memcpy(&af, ap, 16);
        short8 bfg = *(const short8*)&WtO[(size_t)(c16 + l15) * 128 + ks * 32 + quad * 8];
        ha = __builtin_amdgcn_mfma_f32_16x16x32_bf16(af, bfg, ha, 0, 0, 0);
    }
    float part = 0.0f;
    {
        float b1o = out1_b[c16 + l15];
        float o2  = out2_w[c16 + l15];
        #pragma unroll
        for (int r = 0; r < 4; r++)
            part += ssp(ha[r] + b1o) * o2;
    }
    #pragma unroll
    for (int off = 32; off > 0; off >>= 1) part += __shfl_down(part, off);
    if (lane == 0) atomicAdd(&s_red, part);
    __syncthreads();
    if (tid == 0) out[blockIdx.x] = s_red + 32.0f * out2_b[0];
}

extern "C" void kernel_launch(void* const* d_in, const int* in_sizes, int n_in,
                              void* d_out, int out_size, void* d_ws, size_t ws_size,
                              hipStream_t stream)
{
    const int*   z      = (const int*)d_in[0];
    const float* pos    = (const float*)d_in[1];
    const int*   eidx   = (const int*)d_in[3];
    const float* emb    = (const float*)d_in[4];
    const float* mlp_w1 = (const float*)d_in[5];
    const float* mlp_b1 = (const float*)d_in[6];
    const float* mlp_w2 = (const float*)d_in[7];
    const float* mlp_b2 = (const float*)d_in[8];
    const float* cf1_w  = (const float*)d_in[9];
    const float* cf2_w  = (const float*)d_in[10];
    const float* cf2_b  = (const float*)d_in[11];
    const float* lin_w  = (const float*)d_in[12];
    const float* lin_b  = (const float*)d_in[13];
    const float* out1_w = (const float*)d_in[14];
    const float* out1_b = (const float*)d_in[15];
    const float* out2_w = (const float*)d_in[16];
    const float* out2_b = (const float*)d_in[17];
    const int E = in_sizes[3] / 2;

    // workspace carve-up (16B-aligned sections)
    char* p = (char*)d_ws;
    uint2* meta = (uint2*)p;                      p += ((size_t)(E + 1) * 8 + 63) & ~63ULL;
    unsigned int* Tp = (unsigned int*)p;          p += (size_t)3 * KTAB * 128 * 4;
    int* rowptr = (int*)p;                        p += ((size_t)(NATOMS + 1) * 4 + 63) & ~63ULL;
    unsigned short* Wtall = (unsigned short*)p;   // 9*16384 + 64*128 ushorts

    const int EB = (E + NATOMS + 1 + 255) / 256;
    const int WB = (9 * 16384 + 64 * 128 + 255) / 256;
    const int TB = NTILE * 3;
    mega_setup_kernel<<<EB + WB + TB, 256, 0, stream>>>(
        pos, eidx, E, EB, rowptr, cf1_w, cf2_w, lin_w, out1_w, Wtall, meta,
        mlp_w1, mlp_b1, mlp_w2, mlp_b2, Tp);

    fused_schnet_kernel<<<NMOL, 512, 0, stream>>>(
        z, emb, rowptr, meta, Tp, Wtall,
        cf2_b, lin_b, out1_b, out2_w, out2_b, (float*)d_out);
}